// Round 6
// baseline (318.836 us; speedup 1.0000x reference)
//
#include <hip/hip_runtime.h>
#include <hip/hip_bf16.h>

// Problem constants
#define NBS   128
#define NF    182      // 20 text + 150 ocr/obj + 12 decode
#define NP    192      // padded N for MFMA tiling
#define DMODEL 768
#define NH    12
#define HDIM  64
#define SEQT  20
#define ROCR  150
#define NEGV  (-10000.0f)

typedef __attribute__((ext_vector_type(4))) float  f32x4;
typedef __attribute__((ext_vector_type(8))) short  s16x8;
using bf16 = __hip_bfloat16;

#define SB()    __builtin_amdgcn_sched_barrier(0)
#define BAR()   __builtin_amdgcn_s_barrier()
#define LGKM0() asm volatile("s_waitcnt lgkmcnt(0)" ::: "memory")

// global->LDS direct copy, 16B per lane. LDS dest linear in lane (base+lane*16).
__device__ __forceinline__ void gload_lds16(const void* g, void* l) {
    auto gp = (const __attribute__((address_space(1))) unsigned int*)((unsigned long long)g);
    auto lp = (__attribute__((address_space(3))) unsigned int*)(unsigned int)((unsigned long long)l);
    __builtin_amdgcn_global_load_lds(gp, lp, 16, 0, 0);
}

// ---------------------------------------------------------------------------
// Kernel 0: fp32 -> bf16 pre-convert. hs -> hsb; Wq|Wk|Wv -> Wb.
// ---------------------------------------------------------------------------
__global__ __launch_bounds__(256) void convert_bf16(
    const float* __restrict__ hs,
    const float* __restrict__ Wq, const float* __restrict__ Wk, const float* __restrict__ Wv,
    bf16* __restrict__ hsb, bf16* __restrict__ Wb)
{
    const size_t HT = (size_t)NBS * NF * DMODEL / 8;        // 2,236,416
    const size_t WT = 3ull * DMODEL * DMODEL / 8;           // 221,184
    size_t i = (size_t)blockIdx.x * 256 + threadIdx.x;
    if (i >= HT + WT) return;
    const float* src; bf16* dst;
    if (i < HT) {
        size_t e = i * 8; src = hs + e; dst = hsb + e;
    } else {
        size_t e = (i - HT) * 8;
        size_t m = e / ((size_t)DMODEL * DMODEL);
        size_t r = e - m * (size_t)DMODEL * DMODEL;
        src = (m == 0 ? Wq : m == 1 ? Wk : Wv) + r;
        dst = Wb + e;
    }
    float4 a = *reinterpret_cast<const float4*>(src);
    float4 b = *reinterpret_cast<const float4*>(src + 4);
    union { s16x8 v; bf16 h[8]; } u;
    u.h[0] = __float2bfloat16(a.x); u.h[1] = __float2bfloat16(a.y);
    u.h[2] = __float2bfloat16(a.z); u.h[3] = __float2bfloat16(a.w);
    u.h[4] = __float2bfloat16(b.x); u.h[5] = __float2bfloat16(b.y);
    u.h[6] = __float2bfloat16(b.z); u.h[7] = __float2bfloat16(b.w);
    *reinterpret_cast<s16x8*>(dst) = u.v;
}

// ---------------------------------------------------------------------------
// Kernel 1: pack spatial adjacency (b,150,150,12) fp32 -> bitmask (b,12,150,3)
// ---------------------------------------------------------------------------
__global__ __launch_bounds__(256) void pack_adj(const float* __restrict__ adj,
                                                unsigned long long* __restrict__ bits)
{
    __shared__ float tile[ROCR * NH];       // 7.2 KB
    const int b = blockIdx.y, r = blockIdx.x;
    const int tid = threadIdx.x, lane = tid & 63, w = tid >> 6;
    const float* src = adj + ((size_t)b * ROCR + r) * (ROCR * NH);
    for (int i = tid; i < ROCR * NH; i += 256) tile[i] = src[i];
    __syncthreads();
    for (int c = w; c < NH * 3; c += 4) {
        int hh = c / 3, wd = c - hh * 3;
        int k = wd * 64 + lane;
        int j = k - SEQT;
        bool v = false;
        if (j >= 0 && j < ROCR) v = (tile[j * NH + hh] > 0.5f);
        unsigned long long m = __ballot(v);
        if (lane == 0) bits[(((size_t)b * NH + hh) * ROCR + r) * 3 + wd] = m;
    }
}

// ---------------------------------------------------------------------------
// Kernel 2: fused QKV projection, 256x256 8-phase schedule (m201 template).
// C(23296x2304) = hsb x Wb^T + bias. BK=64, 8 waves (2Mx4N), 512 thr,
// LDS 128KB = 2dbuf x (A[256][64] + B[256][64]) bf16, chunk-XOR swizzle
// (linear gload_lds dest + inverse-swizzled global src + swizzled ds_read).
// Per phase: {ds_read quadrant frags || stage 1 half-tile -> barrier ->
// lgkmcnt(0) -> setprio(1) 16 MFMA -> barrier}; vmcnt(4) at ph4/ph8 only.
// Stage schedule (iter i computes kt 2i from d0 [ph1-4], 2i+1 from d1 [ph5-8]):
//   ph1:A0(2i+1)->d1  ph2:A1(2i+1)->d1  ph3:B0(2i+2)->d0  ph4:B1(2i+2)->d0
//   ph5:A0(2i+2)->d0  ph6:A1(2i+2)->d0  ph7:B0(2i+3)->d1  ph8:B1(2i+3)->d1
// (every staged region consumed >=1 barrier earlier; lgkm0-before-endbar
//  closes the cross-wave read window -> write-after-read safe)
// ---------------------------------------------------------------------------
__global__ __launch_bounds__(512, 2) void qkv_gemm(
    const bf16* __restrict__ hsb, const bf16* __restrict__ Wb,
    const float* __restrict__ bq, const float* __restrict__ bk, const float* __restrict__ bv,
    bf16* __restrict__ qw, bf16* __restrict__ kw, bf16* __restrict__ vt)
{
    __shared__ char lds[131072];
    const int tid  = threadIdx.x;
    const int lane = tid & 63;
    const int wid  = tid >> 6;              // 0..7
    const int wm = wid >> 2, wn = wid & 3;  // 2x4 wave grid, each 128x64
    const int lm = lane & 15, lg = lane >> 4;

    // m204 bijective XCD remap over 819 wgs; wgid n-fastest (A-panels
    // disjoint per XCD -> A fetched ~once; B 3.4MB L2/L3-resident).
    const int flat = blockIdx.x;
    const int q8 = 819 / 8, r8 = 819 % 8;   // 102, 3
    const int xcd = flat & 7, off = flat >> 3;
    const int wgid = (xcd < r8 ? xcd * (q8 + 1) : r8 * (q8 + 1) + (xcd - r8) * q8) + off;
    const int my = wgid / 9;
    const int nb = wgid - my * 9;           // 0..8
    const int m0 = my * 256;

    const char* gA = (const char*)hsb + (size_t)m0 * 1536;
    const char* gB = (const char*)Wb  + (size_t)nb * 256 * 1536;

    char* const A0b = lds;
    char* const B0b = lds + 32768;
    char* const A1b = lds + 65536;
    char* const B1b = lds + 98304;

    f32x4 acc[8][4];
    #pragma unroll
    for (int i = 0; i < 8; ++i)
        #pragma unroll
        for (int j = 0; j < 4; ++j) acc[i][j] = (f32x4){0.f, 0.f, 0.f, 0.f};
    s16x8 ar[4][2], br[4][2];

    const int srow = tid >> 3, sch = tid & 7;

    // stage one half-tile (128 rows x 64 cols) of kt into region dstb
    auto ST = [&](char* dstb, const char* gb, int kt, int half) {
        #pragma unroll
        for (int j = 0; j < 2; ++j) {
            int row = half * 128 + j * 64 + srow;
            int lc = sch ^ (row & 7);                     // logical chunk
            gload_lds16(gb + (size_t)row * 1536 + kt * 128 + lc * 16,
                        dstb + row * 128 + sch * 16);
        }
    };
    auto LA = [&](const char* Ab, int mh) {
        #pragma unroll
        for (int f = 0; f < 4; ++f) {
            int r = wm * 128 + mh * 64 + f * 16 + lm;
            const char* p = Ab + r * 128;
            int s = r & 7;
            ar[f][0] = *reinterpret_cast<const s16x8*>(p + ((lg ^ s) << 4));
            ar[f][1] = *reinterpret_cast<const s16x8*>(p + (((4 + lg) ^ s) << 4));
        }
    };
    auto LB = [&](const char* Bb, int nh) {
        #pragma unroll
        for (int f = 0; f < 2; ++f) {
            int ni = nh * 2 + f;
            int r = wn * 64 + ni * 16 + lm;
            const char* p = Bb + r * 128;
            int s = r & 7;
            br[ni][0] = *reinterpret_cast<const s16x8*>(p + ((lg ^ s) << 4));
            br[ni][1] = *reinterpret_cast<const s16x8*>(p + (((4 + lg) ^ s) << 4));
        }
    };
    auto MM = [&](int mh, int nh) {
        __builtin_amdgcn_s_setprio(1);
        #pragma unroll
        for (int f = 0; f < 4; ++f)
            #pragma unroll
            for (int g = 0; g < 2; ++g) {
                int ni = nh * 2 + g;
                acc[mh*4+f][ni] = __builtin_amdgcn_mfma_f32_16x16x32_bf16(ar[f][0], br[ni][0], acc[mh*4+f][ni], 0, 0, 0);
                acc[mh*4+f][ni] = __builtin_amdgcn_mfma_f32_16x16x32_bf16(ar[f][1], br[ni][1], acc[mh*4+f][ni], 0, 0, 0);
            }
        __builtin_amdgcn_s_setprio(0);
    };

    // prologue: kt0 fully -> d0; kt1 B-halves -> d1 (A-halves follow in ph1/2)
    ST(A0b, gA, 0, 0); ST(A0b, gA, 0, 1);
    ST(B0b, gB, 0, 0); ST(B0b, gB, 0, 1);
    ST(B1b, gB, 1, 0); ST(B1b, gB, 1, 1);
    SB(); asm volatile("s_waitcnt vmcnt(4)" ::: "memory"); BAR(); SB();

    for (int i = 0; i < 6; ++i) {
        const int k1 = 2*i+1, k2 = 2*i+2, k3 = 2*i+3;
        const bool st2 = (k2 < 12), st3 = (k3 < 12);
        // ph1
        LA(A0b, 0); LB(B0b, 0);
        ST(A1b, gA, k1, 0);
        SB(); BAR(); LGKM0(); SB();
        MM(0, 0);
        SB(); BAR();
        // ph2
        LB(B0b, 1);
        ST(A1b, gA, k1, 1);
        SB(); BAR(); LGKM0(); SB();
        MM(0, 1);
        SB(); BAR();
        // ph3
        LA(A0b, 1);
        if (st2) ST(B0b, gB, k2, 0);
        SB(); BAR(); LGKM0(); SB();
        MM(1, 0);
        SB(); BAR();
        // ph4
        if (st2) ST(B0b, gB, k2, 1);
        SB(); BAR(); LGKM0(); SB();
        MM(1, 1);
        SB();
        if (i < 5) { asm volatile("s_waitcnt vmcnt(4)" ::: "memory"); }
        else       { asm volatile("s_waitcnt vmcnt(0)" ::: "memory"); }
        BAR();
        // ph5
        LA(A1b, 0); LB(B1b, 0);
        if (st2) ST(A0b, gA, k2, 0);
        SB(); BAR(); LGKM0(); SB();
        MM(0, 0);
        SB(); BAR();
        // ph6
        LB(B1b, 1);
        if (st2) ST(A0b, gA, k2, 1);
        SB(); BAR(); LGKM0(); SB();
        MM(0, 1);
        SB(); BAR();
        // ph7
        LA(A1b, 1);
        if (st3) ST(B1b, gB, k3, 0);
        SB(); BAR(); LGKM0(); SB();
        MM(1, 0);
        SB(); BAR();
        // ph8
        if (st3) ST(B1b, gB, k3, 1);
        SB(); BAR(); LGKM0(); SB();
        MM(1, 1);
        SB();
        if (i < 5) { asm volatile("s_waitcnt vmcnt(4)" ::: "memory"); }
        BAR();
    }

    // epilogue
    const int which = nb / 3;
    const int n0    = (nb - which * 3) * 256;
    const float* bias = (which == 0) ? bq : (which == 1) ? bk : bv;
    bf16* outp        = (which == 0) ? qw : kw;
    #pragma unroll
    for (int ni = 0; ni < 4; ++ni) {
        int col = n0 + wn * 64 + ni * 16 + lm;
        float bcol = bias[col];
        #pragma unroll
        for (int mi = 0; mi < 8; ++mi) {
            #pragma unroll
            for (int j = 0; j < 4; ++j) {
                int row = m0 + wm * 128 + mi * 16 + lg * 4 + j;
                float val = acc[mi][ni][j] + bcol;
                if (which == 2) {
                    int bb = row / NF, key = row - bb * NF;
                    int hh = col >> 6, d = col & 63;
                    vt[(((size_t)bb * NH + hh) * HDIM + d) * NP + key] = __float2bfloat16(val);
                } else {
                    outp[(size_t)row * DMODEL + col] = __float2bfloat16(val);
                }
            }
        }
    }
}

// ---------------------------------------------------------------------------
// Kernel 3: MFMA attention (unchanged — verified). One block per (b,h).
// ---------------------------------------------------------------------------
__global__ __launch_bounds__(256) void attn_mfma(
    const bf16* __restrict__ qw, const bf16* __restrict__ kw, const bf16* __restrict__ vt,
    const float* __restrict__ amask,
    const unsigned long long* __restrict__ bits,
    float* __restrict__ out)
{
    const int bh = blockIdx.x;
    const int b = bh / NH, h = bh - b * NH;
    const int tid = threadIdx.x, lane = tid & 63, wid = tid >> 6;
    const int lm = lane & 15, lg = lane >> 4;

    __shared__ bf16 Ksh[NP * HDIM];                 // 24 KB, XOR-swizzled rows
    __shared__ bf16 Psh[4][16 * NP];                // 24 KB, per-wave, swizzled
    __shared__ unsigned long long Lw[NP][3];        // 4.6 KB
    __shared__ unsigned long long aw[3];

    if (wid == 0) {
        #pragma unroll
        for (int w = 0; w < 3; ++w) {
            int k = w * 64 + lane;
            bool v = (k < NF) && (amask[b * NF + k] == 0.0f);
            unsigned long long m = __ballot(v);
            if (lane == 0) aw[w] = m;
        }
    }
    {
        const bf16* kbase = kw + (size_t)b * NF * DMODEL + h * HDIM;
        for (int c = tid; c < NP * 8; c += 256) {
            int row = c >> 3, cc = c & 7;
            int byteoff = row * 128 + ((cc * 16) ^ ((row & 7) << 4));
            s16x8 v;
            if (row < NF) v = *reinterpret_cast<const s16x8*>(kbase + (size_t)row * DMODEL + cc * 8);
            else          v = (s16x8){0,0,0,0,0,0,0,0};
            *reinterpret_cast<s16x8*>((char*)Ksh + byteoff) = v;
        }
    }
    {
        float* obase = out + (size_t)b * NF * DMODEL + h * HDIM;
        for (int i = tid; i < 12 * 64; i += 256)
            obase[(size_t)(170 + (i >> 6)) * DMODEL + (i & 63)] = 0.f;
    }
    __syncthreads();
    if (tid < NP) {
        int r = tid;
        unsigned long long s0 = 0, s1 = 0, s2 = 0;
        const unsigned long long DEC = 0xFFFull << 42;
        if (r < SEQT) {
            s2 = DEC;
        } else if (r < SEQT + ROCR) {
            const unsigned long long* bp = bits + (((size_t)b * NH + h) * ROCR + (r - SEQT)) * 3;
            s0 = bp[0]; s1 = bp[1]; s2 = bp[2] | DEC;
        }
        Lw[r][0] = s0 & aw[0];
        Lw[r][1] = s1 & aw[1];
        Lw[r][2] = s2 & aw[2];
    }
    __syncthreads();

    const bf16* qbase = qw + (size_t)b * NF * DMODEL + h * HDIM;
    const bf16* vbase = vt + (size_t)bh * HDIM * NP;
    float*      obase = out + (size_t)b * NF * DMODEL + h * HDIM;
    char* Pw = (char*)Psh + wid * (16 * NP * 2);

    for (int band = wid; band < 11; band += 4) {
        const int q0 = band * 16;
        s16x8 qf0 = *reinterpret_cast<const s16x8*>(qbase + (size_t)(q0 + lm) * DMODEL + lg * 8);
        s16x8 qf1 = *reinterpret_cast<const s16x8*>(qbase + (size_t)(q0 + lm) * DMODEL + 32 + lg * 8);

        f32x4 sacc[12];
        #pragma unroll
        for (int t = 0; t < 12; ++t) sacc[t] = (f32x4){0.f, 0.f, 0.f, 0.f};
        #pragma unroll
        for (int t = 0; t < 12; ++t) {
            int key = t * 16 + lm;
            const char* kb = (const char*)Ksh + key * 128;
            int sw = (key & 7) << 4;
            s16x8 kf0 = *reinterpret_cast<const s16x8*>(kb + ((lg * 16) ^ sw));
            s16x8 kf1 = *reinterpret_cast<const s16x8*>(kb + ((64 + lg * 16) ^ sw));
            sacc[t] = __builtin_amdgcn_mfma_f32_16x16x32_bf16(qf0, kf0, sacc[t], 0, 0, 0);
            sacc[t] = __builtin_amdgcn_mfma_f32_16x16x32_bf16(qf1, kf1, sacc[t], 0, 0, 0);
        }

        float scl[4];
        #pragma unroll
        for (int j = 0; j < 4; ++j) {
            int row = q0 + lg * 4 + j;
            unsigned long long w0 = Lw[row][0], w1 = Lw[row][1], w2 = Lw[row][2];
            float mx = -3.0e38f;
            #pragma unroll
            for (int t = 0; t < 12; ++t) {
                unsigned long long w = (t < 4) ? w0 : (t < 8) ? w1 : w2;
                int sh = ((t & 3) << 4) + lm;
                float s = sacc[t][j] * 0.125f;
                s = ((w >> sh) & 1ull) ? s : -3.0e38f;
                sacc[t][j] = s;
                mx = fmaxf(mx, s);
            }
            mx = fmaxf(mx, __shfl_xor(mx, 1));
            mx = fmaxf(mx, __shfl_xor(mx, 2));
            mx = fmaxf(mx, __shfl_xor(mx, 4));
            mx = fmaxf(mx, __shfl_xor(mx, 8));
            float sum = 0.f;
            #pragma unroll
            for (int t = 0; t < 12; ++t) {
                float e = (sacc[t][j] > -1.0e37f) ? __expf(sacc[t][j] - mx) : 0.f;
                sacc[t][j] = e;
                sum += e;
            }
            sum += __shfl_xor(sum, 1);
            sum += __shfl_xor(sum, 2);
            sum += __shfl_xor(sum, 4);
            sum += __shfl_xor(sum, 8);
            scl[j] = (mx > -1.0e37f) ? 1.0f / sum : 0.f;
        }

        #pragma unroll
        for (int j = 0; j < 4; ++j) {
            int prow = lg * 4 + j;
            int sw = (prow & 7) << 4;
            char* prb = Pw + prow * (NP * 2);
            #pragma unroll
            for (int t = 0; t < 12; ++t) {
                bf16 pv = __float2bfloat16(sacc[t][j] * scl[j]);
                *reinterpret_cast<unsigned short*>(prb + (((t * 16 + lm) * 2) ^ sw)) =
                    *reinterpret_cast<unsigned short*>(&pv);
            }
        }
        asm volatile("s_waitcnt lgkmcnt(0)" ::: "memory");
        __builtin_amdgcn_sched_barrier(0);

        f32x4 oacc[4];
        #pragma unroll
        for (int t = 0; t < 4; ++t) oacc[t] = (f32x4){0.f, 0.f, 0.f, 0.f};
        int psw = (lm & 7) << 4;
        #pragma unroll
        for (int ks = 0; ks < 6; ++ks) {
            s16x8 pf = *reinterpret_cast<const s16x8*>(Pw + lm * (NP * 2) + ((ks * 64 + lg * 16) ^ psw));
            #pragma unroll
            for (int t = 0; t < 4; ++t) {
                int d = t * 16 + lm;
                s16x8 vf = *reinterpret_cast<const s16x8*>(vbase + (size_t)d * NP + ks * 32 + lg * 8);
                oacc[t] = __builtin_amdgcn_mfma_f32_16x16x32_bf16(pf, vf, oacc[t], 0, 0, 0);
            }
        }
        #pragma unroll
        for (int j = 0; j < 4; ++j) {
            int row = q0 + lg * 4 + j;
            if (row < 170) {
                #pragma unroll
                for (int t = 0; t < 4; ++t)
                    obase[(size_t)row * DMODEL + t * 16 + lm] = oacc[t][j];
            }
        }
    }
}

// ---------------------------------------------------------------------------
extern "C" void kernel_launch(void* const* d_in, const int* in_sizes, int n_in,
                              void* d_out, int out_size, void* d_ws, size_t ws_size,
                              hipStream_t stream)
{
    const float* hs    = (const float*)d_in[0];
    const float* amask = (const float*)d_in[1];
    const float* adj   = (const float*)d_in[2];
    const float* Wq    = (const float*)d_in[3];
    const float* bq    = (const float*)d_in[4];
    const float* Wk    = (const float*)d_in[5];
    const float* bk    = (const float*)d_in[6];
    const float* Wv    = (const float*)d_in[7];
    const float* bv    = (const float*)d_in[8];
    float* out = (float*)d_out;

    const size_t QKV = (size_t)NBS * NF * DMODEL;          // 17,891,328
    const size_t VT  = (size_t)NBS * NH * HDIM * NP;       // 18,874,368
    char* ws = (char*)d_ws;
    bf16* Wb = (bf16*)ws;                                  // 3.5 MB
    bf16* qw = (bf16*)(ws + 3538944ull * 2);
    bf16* kw = (bf16*)(ws + 3538944ull * 2 + QKV * 2);
    bf16* vt = (bf16*)(ws + 3538944ull * 2 + QKV * 4);
    unsigned long long* bits = (unsigned long long*)(ws + 3538944ull * 2 + QKV * 4 + VT * 2);
    bf16* hsb = (bf16*)d_out;   // attn fully rewrites d_out afterwards (stream-ordered)

    const int cvt_blocks = (int)(((size_t)NBS * NF * DMODEL / 8 + 3ull * DMODEL * DMODEL / 8 + 255) / 256);
    convert_bf16<<<cvt_blocks, 256, 0, stream>>>(hs, Wq, Wk, Wv, hsb, Wb);
    pack_adj<<<dim3(ROCR, NBS), 256, 0, stream>>>(adj, bits);
    qkv_gemm<<<dim3(819), 512, 0, stream>>>(hsb, Wb, bq, bk, bv, qw, kw, vt);
    attn_mfma<<<dim3(NBS * NH), 256, 0, stream>>>(qw, kw, vt, amask, bits, out);
}

// Round 7
// 300.976 us; speedup vs baseline: 1.0593x; 1.0593x over previous
//
#include <hip/hip_runtime.h>
#include <hip/hip_bf16.h>

// Problem constants
#define NBS   128
#define NF    182      // 20 text + 150 ocr/obj + 12 decode
#define NP    192      // padded N for MFMA tiling
#define DMODEL 768
#define NH    12
#define HDIM  64
#define SEQT  20
#define ROCR  150
#define NEGV  (-10000.0f)

typedef __attribute__((ext_vector_type(4))) float  f32x4;
typedef __attribute__((ext_vector_type(8))) short  s16x8;
using bf16 = __hip_bfloat16;

#define SB()    __builtin_amdgcn_sched_barrier(0)
#define BAR()   __builtin_amdgcn_s_barrier()

// global->LDS direct copy, 16B per lane. LDS dest linear in lane (base+lane*16).
__device__ __forceinline__ void gload_lds16(const void* g, void* l) {
    auto gp = (const __attribute__((address_space(1))) unsigned int*)((unsigned long long)g);
    auto lp = (__attribute__((address_space(3))) unsigned int*)(unsigned int)((unsigned long long)l);
    __builtin_amdgcn_global_load_lds(gp, lp, 16, 0, 0);
}

// ---------------------------------------------------------------------------
// Kernel 0: fp32 -> bf16 pre-convert. hs -> hsb; Wq|Wk|Wv -> Wb.
// ---------------------------------------------------------------------------
__global__ __launch_bounds__(256) void convert_bf16(
    const float* __restrict__ hs,
    const float* __restrict__ Wq, const float* __restrict__ Wk, const float* __restrict__ Wv,
    bf16* __restrict__ hsb, bf16* __restrict__ Wb)
{
    const size_t HT = (size_t)NBS * NF * DMODEL / 8;        // 2,236,416
    const size_t WT = 3ull * DMODEL * DMODEL / 8;           // 221,184
    size_t i = (size_t)blockIdx.x * 256 + threadIdx.x;
    if (i >= HT + WT) return;
    const float* src; bf16* dst;
    if (i < HT) {
        size_t e = i * 8; src = hs + e; dst = hsb + e;
    } else {
        size_t e = (i - HT) * 8;
        size_t m = e / ((size_t)DMODEL * DMODEL);
        size_t r = e - m * (size_t)DMODEL * DMODEL;
        src = (m == 0 ? Wq : m == 1 ? Wk : Wv) + r;
        dst = Wb + e;
    }
    float4 a = *reinterpret_cast<const float4*>(src);
    float4 b = *reinterpret_cast<const float4*>(src + 4);
    union { s16x8 v; bf16 h[8]; } u;
    u.h[0] = __float2bfloat16(a.x); u.h[1] = __float2bfloat16(a.y);
    u.h[2] = __float2bfloat16(a.z); u.h[3] = __float2bfloat16(a.w);
    u.h[4] = __float2bfloat16(b.x); u.h[5] = __float2bfloat16(b.y);
    u.h[6] = __float2bfloat16(b.z); u.h[7] = __float2bfloat16(b.w);
    *reinterpret_cast<s16x8*>(dst) = u.v;
}

// ---------------------------------------------------------------------------
// Kernel 1: pack spatial adjacency (b,150,150,12) fp32 -> bitmask (b,12,150,3)
// ---------------------------------------------------------------------------
__global__ __launch_bounds__(256) void pack_adj(const float* __restrict__ adj,
                                                unsigned long long* __restrict__ bits)
{
    __shared__ float tile[ROCR * NH];       // 7.2 KB
    const int b = blockIdx.y, r = blockIdx.x;
    const int tid = threadIdx.x, lane = tid & 63, w = tid >> 6;
    const float* src = adj + ((size_t)b * ROCR + r) * (ROCR * NH);
    for (int i = tid; i < ROCR * NH; i += 256) tile[i] = src[i];
    __syncthreads();
    for (int c = w; c < NH * 3; c += 4) {
        int hh = c / 3, wd = c - hh * 3;
        int k = wd * 64 + lane;
        int j = k - SEQT;
        bool v = false;
        if (j >= 0 && j < ROCR) v = (tile[j * NH + hh] > 0.5f);
        unsigned long long m = __ballot(v);
        if (lane == 0) bits[(((size_t)b * NH + hh) * ROCR + r) * 3 + wd] = m;
    }
}

// ---------------------------------------------------------------------------
// Kernel 2: fused QKV projection. C(23296x2304) = hsb x Wb^T + bias.
// 128x128 tile, BK=32, 32KB LDS double buffer -> 4 blocks/CU (TLP for short-K),
// counted vmcnt(4) + raw barriers, chunk-XOR swizzle on 64B rows:
// phys chunk p holds logical chunk p^((row>>1)&3) -> fragment ds_read covers
// all 32 banks at 2 lanes/bank (free). Linear gload_lds dest, pre-swizzled
// global src, swizzled ds_read. m204 bijective XCD remap, n-fastest wgid.
// q,k token-major; V transposed per head: vt[(bh*64+d)*192 + key].
// ---------------------------------------------------------------------------
__global__ __launch_bounds__(256, 4) void qkv_gemm(
    const bf16* __restrict__ hsb, const bf16* __restrict__ Wb,
    const float* __restrict__ bq, const float* __restrict__ bk, const float* __restrict__ bv,
    bf16* __restrict__ qw, bf16* __restrict__ kw, bf16* __restrict__ vt)
{
    __shared__ char lds[32768];             // 2 x (A 8KB + B 8KB)
    const int tid  = threadIdx.x;
    const int lane = tid & 63;
    const int wid  = tid >> 6;
    const int wr = wid >> 1, wc = wid & 1;  // 2x2 wave grid, 64x64 each
    const int lm = lane & 15, lg = lane >> 4;

    // m204 bijective XCD remap over 3276 wgs; wgid m-major (n fastest):
    // one XCD reuses the same A panel, B (3.5MB) L2/L3-resident.
    const int flat = blockIdx.x;            // 0..3275
    const int q8 = 3276 / 8, r8 = 3276 % 8; // 409, 4
    const int xcd = flat & 7, off = flat >> 3;
    const int wgid = (xcd < r8 ? xcd * (q8 + 1) : r8 * (q8 + 1) + (xcd - r8) * q8) + off;
    const int my = wgid / 18;
    const int gy = wgid - my * 18;          // 0..17 column slab
    const int m0 = my * 128;

    const char* gA = (const char*)hsb + (size_t)m0 * 1536;
    const char* gB = (const char*)Wb  + (size_t)gy * 128 * 1536;

    const int srow = tid >> 2;              // 0..63
    const int sch  = tid & 3;               // phys 16B chunk within 64B row

    f32x4 acc[4][4];
    #pragma unroll
    for (int i = 0; i < 4; ++i)
        #pragma unroll
        for (int j = 0; j < 4; ++j) acc[i][j] = (f32x4){0.f, 0.f, 0.f, 0.f};

    const int arow = wr * 64 + lm;          // + mi*16
    const int brow = wc * 64 + lm;          // + ni*16

    // stage K-tile kt (128 rows x 32 cols A and B) into buffer dstb; 4 loads/thr
    auto ST = [&](int kt, char* dstb) {
        #pragma unroll
        for (int it = 0; it < 2; ++it) {
            int row = it * 64 + srow;
            int lc = sch ^ ((row >> 1) & 3);            // logical chunk
            size_t gofs = (size_t)row * 1536 + (size_t)kt * 64 + lc * 16;
            int o = row * 64 + sch * 16;
            gload_lds16(gA + gofs, dstb + o);
            gload_lds16(gB + gofs, dstb + 8192 + o);
        }
    };
    auto CP = [&](const char* buf) {
        const char* Ab = buf;
        const char* Bb = buf + 8192;
        s16x8 af[4], bfv[4];
        #pragma unroll
        for (int mi = 0; mi < 4; ++mi) {
            int r = arow + mi * 16;
            af[mi] = *reinterpret_cast<const s16x8*>(Ab + r * 64 + ((lg ^ ((r >> 1) & 3)) << 4));
        }
        #pragma unroll
        for (int ni = 0; ni < 4; ++ni) {
            int r = brow + ni * 16;
            bfv[ni] = *reinterpret_cast<const s16x8*>(Bb + r * 64 + ((lg ^ ((r >> 1) & 3)) << 4));
        }
        #pragma unroll
        for (int mi = 0; mi < 4; ++mi)
            #pragma unroll
            for (int ni = 0; ni < 4; ++ni)
                acc[mi][ni] = __builtin_amdgcn_mfma_f32_16x16x32_bf16(af[mi], bfv[ni], acc[mi][ni], 0, 0, 0);
    };

    // prologue: two K-tiles in flight
    ST(0, lds);
    ST(1, lds + 16384);

    for (int t = 0; t < 24; ++t) {
        // wait stage(t) done; stage(t+1)'s 4 loads stay in flight
        if (t < 23) { asm volatile("s_waitcnt vmcnt(4)" ::: "memory"); }
        else        { asm volatile("s_waitcnt vmcnt(0)" ::: "memory"); }
        SB(); BAR(); SB();
        CP(lds + (t & 1) * 16384);
        SB(); BAR();                        // buf[t&1] free for overwrite
        if (t + 2 < 24) ST(t + 2, lds + (t & 1) * 16384);
    }

    const int which = gy / 6;
    const int n0    = (gy - which * 6) * 128;       // col offset within 768
    const float* bias = (which == 0) ? bq : (which == 1) ? bk : bv;
    bf16* outp        = (which == 0) ? qw : kw;
    #pragma unroll
    for (int ni = 0; ni < 4; ++ni) {
        int col = n0 + wc * 64 + ni * 16 + lm;
        float bcol = bias[col];
        #pragma unroll
        for (int mi = 0; mi < 4; ++mi) {
            #pragma unroll
            for (int j = 0; j < 4; ++j) {
                int row = m0 + wr * 64 + mi * 16 + lg * 4 + j;
                float val = acc[mi][ni][j] + bcol;
                if (which == 2) {
                    int bb = row / NF, key = row - bb * NF;
                    int hh = col >> 6, d = col & 63;
                    vt[(((size_t)bb * NH + hh) * HDIM + d) * NP + key] = __float2bfloat16(val);
                } else {
                    outp[(size_t)row * DMODEL + col] = __float2bfloat16(val);
                }
            }
        }
    }
}

// ---------------------------------------------------------------------------
// Kernel 3: MFMA attention (unchanged — verified). One block per (b,h).
// ---------------------------------------------------------------------------
__global__ __launch_bounds__(256) void attn_mfma(
    const bf16* __restrict__ qw, const bf16* __restrict__ kw, const bf16* __restrict__ vt,
    const float* __restrict__ amask,
    const unsigned long long* __restrict__ bits,
    float* __restrict__ out)
{
    const int bh = blockIdx.x;
    const int b = bh / NH, h = bh - b * NH;
    const int tid = threadIdx.x, lane = tid & 63, wid = tid >> 6;
    const int lm = lane & 15, lg = lane >> 4;

    __shared__ bf16 Ksh[NP * HDIM];                 // 24 KB, XOR-swizzled rows
    __shared__ bf16 Psh[4][16 * NP];                // 24 KB, per-wave, swizzled
    __shared__ unsigned long long Lw[NP][3];        // 4.6 KB
    __shared__ unsigned long long aw[3];

    if (wid == 0) {
        #pragma unroll
        for (int w = 0; w < 3; ++w) {
            int k = w * 64 + lane;
            bool v = (k < NF) && (amask[b * NF + k] == 0.0f);
            unsigned long long m = __ballot(v);
            if (lane == 0) aw[w] = m;
        }
    }
    {
        const bf16* kbase = kw + (size_t)b * NF * DMODEL + h * HDIM;
        for (int c = tid; c < NP * 8; c += 256) {
            int row = c >> 3, cc = c & 7;
            int byteoff = row * 128 + ((cc * 16) ^ ((row & 7) << 4));
            s16x8 v;
            if (row < NF) v = *reinterpret_cast<const s16x8*>(kbase + (size_t)row * DMODEL + cc * 8);
            else          v = (s16x8){0,0,0,0,0,0,0,0};
            *reinterpret_cast<s16x8*>((char*)Ksh + byteoff) = v;
        }
    }
    {
        float* obase = out + (size_t)b * NF * DMODEL + h * HDIM;
        for (int i = tid; i < 12 * 64; i += 256)
            obase[(size_t)(170 + (i >> 6)) * DMODEL + (i & 63)] = 0.f;
    }
    __syncthreads();
    if (tid < NP) {
        int r = tid;
        unsigned long long s0 = 0, s1 = 0, s2 = 0;
        const unsigned long long DEC = 0xFFFull << 42;
        if (r < SEQT) {
            s2 = DEC;
        } else if (r < SEQT + ROCR) {
            const unsigned long long* bp = bits + (((size_t)b * NH + h) * ROCR + (r - SEQT)) * 3;
            s0 = bp[0]; s1 = bp[1]; s2 = bp[2] | DEC;
        }
        Lw[r][0] = s0 & aw[0];
        Lw[r][1] = s1 & aw[1];
        Lw[r][2] = s2 & aw[2];
    }
    __syncthreads();

    const bf16* qbase = qw + (size_t)b * NF * DMODEL + h * HDIM;
    const bf16* vbase = vt + (size_t)bh * HDIM * NP;
    float*      obase = out + (size_t)b * NF * DMODEL + h * HDIM;
    char* Pw = (char*)Psh + wid * (16 * NP * 2);

    for (int band = wid; band < 11; band += 4) {
        const int q0 = band * 16;
        s16x8 qf0 = *reinterpret_cast<const s16x8*>(qbase + (size_t)(q0 + lm) * DMODEL + lg * 8);
        s16x8 qf1 = *reinterpret_cast<const s16x8*>(qbase + (size_t)(q0 + lm) * DMODEL + 32 + lg * 8);

        f32x4 sacc[12];
        #pragma unroll
        for (int t = 0; t < 12; ++t) sacc[t] = (f32x4){0.f, 0.f, 0.f, 0.f};
        #pragma unroll
        for (int t = 0; t < 12; ++t) {
            int key = t * 16 + lm;
            const char* kb = (const char*)Ksh + key * 128;
            int sw = (key & 7) << 4;
            s16x8 kf0 = *reinterpret_cast<const s16x8*>(kb + ((lg * 16) ^ sw));
            s16x8 kf1 = *reinterpret_cast<const s16x8*>(kb + ((64 + lg * 16) ^ sw));
            sacc[t] = __builtin_amdgcn_mfma_f32_16x16x32_bf16(qf0, kf0, sacc[t], 0, 0, 0);
            sacc[t] = __builtin_amdgcn_mfma_f32_16x16x32_bf16(qf1, kf1, sacc[t], 0, 0, 0);
        }

        float scl[4];
        #pragma unroll
        for (int j = 0; j < 4; ++j) {
            int row = q0 + lg * 4 + j;
            unsigned long long w0 = Lw[row][0], w1 = Lw[row][1], w2 = Lw[row][2];
            float mx = -3.0e38f;
            #pragma unroll
            for (int t = 0; t < 12; ++t) {
                unsigned long long w = (t < 4) ? w0 : (t < 8) ? w1 : w2;
                int sh = ((t & 3) << 4) + lm;
                float s = sacc[t][j] * 0.125f;
                s = ((w >> sh) & 1ull) ? s : -3.0e38f;
                sacc[t][j] = s;
                mx = fmaxf(mx, s);
            }
            mx = fmaxf(mx, __shfl_xor(mx, 1));
            mx = fmaxf(mx, __shfl_xor(mx, 2));
            mx = fmaxf(mx, __shfl_xor(mx, 4));
            mx = fmaxf(mx, __shfl_xor(mx, 8));
            float sum = 0.f;
            #pragma unroll
            for (int t = 0; t < 12; ++t) {
                float e = (sacc[t][j] > -1.0e37f) ? __expf(sacc[t][j] - mx) : 0.f;
                sacc[t][j] = e;
                sum += e;
            }
            sum += __shfl_xor(sum, 1);
            sum += __shfl_xor(sum, 2);
            sum += __shfl_xor(sum, 4);
            sum += __shfl_xor(sum, 8);
            scl[j] = (mx > -1.0e37f) ? 1.0f / sum : 0.f;
        }

        #pragma unroll
        for (int j = 0; j < 4; ++j) {
            int prow = lg * 4 + j;
            int sw = (prow & 7) << 4;
            char* prb = Pw + prow * (NP * 2);
            #pragma unroll
            for (int t = 0; t < 12; ++t) {
                bf16 pv = __float2bfloat16(sacc[t][j] * scl[j]);
                *reinterpret_cast<unsigned short*>(prb + (((t * 16 + lm) * 2) ^ sw)) =
                    *reinterpret_cast<unsigned short*>(&pv);
            }
        }
        asm volatile("s_waitcnt lgkmcnt(0)" ::: "memory");
        __builtin_amdgcn_sched_barrier(0);

        f32x4 oacc[4];
        #pragma unroll
        for (int t = 0; t < 4; ++t) oacc[t] = (f32x4){0.f, 0.f, 0.f, 0.f};
        int psw = (lm & 7) << 4;
        #pragma unroll
        for (int ks = 0; ks < 6; ++ks) {
            s16x8 pf = *reinterpret_cast<const s16x8*>(Pw + lm * (NP * 2) + ((ks * 64 + lg * 16) ^ psw));
            #pragma unroll
            for (int t = 0; t < 4; ++t) {
                int d = t * 16 + lm;
                s16x8 vf = *reinterpret_cast<const s16x8*>(vbase + (size_t)d * NP + ks * 32 + lg * 8);
                oacc[t] = __builtin_amdgcn_mfma_f32_16x16x32_bf16(pf, vf, oacc[t], 0, 0, 0);
            }
        }
        #pragma unroll
        for (int j = 0; j < 4; ++j) {
            int row = q0 + lg * 4 + j;
            if (row < 170) {
                #pragma unroll
                for (int t = 0; t < 4; ++t)
                    obase[(size_t)row * DMODEL + t * 16 + lm] = oacc[t][j];
            }
        }
    }
}

// ---------------------------------------------------------------------------
extern "C" void kernel_launch(void* const* d_in, const int* in_sizes, int n_in,
                              void* d_out, int out_size, void* d_ws, size_t ws_size,
                              hipStream_t stream)
{
    const float* hs    = (const float*)d_in[0];
    const float* amask = (const float*)d_in[1];
    const float* adj   = (const float*)d_in[2];
    const float* Wq    = (const float*)d_in[3];
    const float* bq    = (const float*)d_in[4];
    const float* Wk    = (const float*)d_in[5];
    const float* bk    = (const float*)d_in[6];
    const float* Wv    = (const float*)d_in[7];
    const float* bv    = (const float*)d_in[8];
    float* out = (float*)d_out;

    const size_t QKV = (size_t)NBS * NF * DMODEL;          // 17,891,328
    const size_t VT  = (size_t)NBS * NH * HDIM * NP;       // 18,874,368
    char* ws = (char*)d_ws;
    bf16* Wb = (bf16*)ws;                                  // 3.5 MB
    bf16* qw = (bf16*)(ws + 3538944ull * 2);
    bf16* kw = (bf16*)(ws + 3538944ull * 2 + QKV * 2);
    bf16* vt = (bf16*)(ws + 3538944ull * 2 + QKV * 4);
    unsigned long long* bits = (unsigned long long*)(ws + 3538944ull * 2 + QKV * 4 + VT * 2);
    bf16* hsb = (bf16*)d_out;   // attn fully rewrites d_out afterwards (stream-ordered)

    const int cvt_blocks = (int)(((size_t)NBS * NF * DMODEL / 8 + 3ull * DMODEL * DMODEL / 8 + 255) / 256);
    convert_bf16<<<cvt_blocks, 256, 0, stream>>>(hs, Wq, Wk, Wv, hsb, Wb);
    pack_adj<<<dim3(ROCR, NBS), 256, 0, stream>>>(adj, bits);
    qkv_gemm<<<dim3(3276), 256, 0, stream>>>(hsb, Wb, bq, bk, bv, qw, kw, vt);
    attn_mfma<<<dim3(NBS * NH), 256, 0, stream>>>(qw, kw, vt, amask, bits, out);
}